// Round 22
// baseline (231.259 us; speedup 1.0000x reference)
//
#include <hip/hip_runtime.h>
#include <hip/hip_bf16.h>
#include <cstdint>
#include <cstddef>

#define T_ 512
#define DF 64
#define NPAIR 120
#define STEPW 16
#define NEGS (-(1 << 26))
#define NSK 640   // skewed-W rows per pair (638 used, padded)
#define NSEQ 128

// softmin constants
#define C1_ 0.28853900817779268f   // log2(e)/5
#define C2D 3.4657359027997265     // 5*ln(2), double

typedef unsigned short ushort_t;
using f32x4 = __attribute__((ext_vector_type(4))) float;
using bf16x8 = __attribute__((ext_vector_type(8))) short;

struct ushort4_t { ushort_t x, y, z, w; };

__device__ __forceinline__ float wred_sum(float v) {
#pragma unroll
  for (int o = 32; o > 0; o >>= 1) v += __shfl_down(v, o);
  return v;  // lane 0 holds the total
}

__device__ __forceinline__ int dexp(double x) {
  return (int)((__double_as_longlong(x) >> 52) & 0x7ff) - 1023;
}

__device__ __forceinline__ ushort_t f2bf(float x) {
  __hip_bfloat16 h = __float2bfloat16(x);
  return *reinterpret_cast<ushort_t*>(&h);
}
__device__ __forceinline__ float bf2f(ushort_t u) {
  __hip_bfloat16 h = *reinterpret_cast<__hip_bfloat16*>(&u);
  return __bfloat162float(h);
}

// unsinkable 16B global load to a named VGPR quad (HK pattern)
#define GLOAD(DST, PTR)                                                    \
  asm volatile("global_load_dwordx4 %0, %1, off"                           \
               : "=&v"(DST) : "v"(PTR) : "memory")

// ---------------------------------------------------------------------------
// Kernel 0: PREP — one-shot split-bf16 conversion of all 128 sequences +
// per-row norms. Removes the per-tile conversion redundancy (each anchor was
// re-converted 960x inside gemm; r21 post-mortem put gemm at ~59 us with
// conversion VALU + serial norm loop dominating).
// Block b: seq = b>>3, row-group rg = b&7 (64 rows).
// ---------------------------------------------------------------------------
__global__ __launch_bounds__(256) void prep_kernel(
    const float* __restrict__ data, ushort_t* __restrict__ xh,
    ushort_t* __restrict__ xl, float* __restrict__ nrm) {
  __shared__ float part[64][17];
  const int seq = blockIdx.x >> 3;
  const int rg = blockIdx.x & 7;
  const int tid = threadIdx.x;
  const float* src = data + (size_t)seq * (T_ * DF) + (size_t)rg * 64 * DF;
  ushort_t* dh = xh + (size_t)seq * (T_ * DF) + (size_t)rg * 64 * DF;
  ushort_t* dl = xl + (size_t)seq * (T_ * DF) + (size_t)rg * 64 * DF;

#pragma unroll
  for (int l = 0; l < 4; ++l) {
    int idx = tid + l * 256;   // 0..1023
    int r = idx >> 4;          // row within group
    int c = idx & 15;          // 4-col chunk
    float4 v = reinterpret_cast<const float4*>(src + (size_t)r * DF)[c];
    const float xa[4] = {v.x, v.y, v.z, v.w};
    ushort4_t h4, l4;
    float s = 0.f;
    ushort_t hh, ll;
    hh = f2bf(xa[0]); ll = f2bf(xa[0] - bf2f(hh));
    h4.x = hh; l4.x = ll;
    { float rec = bf2f(hh) + bf2f(ll); s = fmaf(rec, rec, s); }
    hh = f2bf(xa[1]); ll = f2bf(xa[1] - bf2f(hh));
    h4.y = hh; l4.y = ll;
    { float rec = bf2f(hh) + bf2f(ll); s = fmaf(rec, rec, s); }
    hh = f2bf(xa[2]); ll = f2bf(xa[2] - bf2f(hh));
    h4.z = hh; l4.z = ll;
    { float rec = bf2f(hh) + bf2f(ll); s = fmaf(rec, rec, s); }
    hh = f2bf(xa[3]); ll = f2bf(xa[3] - bf2f(hh));
    h4.w = hh; l4.w = ll;
    { float rec = bf2f(hh) + bf2f(ll); s = fmaf(rec, rec, s); }
    reinterpret_cast<ushort4_t*>(dh + (size_t)r * DF)[c] = h4;
    reinterpret_cast<ushort4_t*>(dl + (size_t)r * DF)[c] = l4;
    part[r][c] = s;
  }
  __syncthreads();
  if (tid < 64) {
    float s = 0.f;
#pragma unroll
    for (int c = 0; c < 16; ++c) s += part[tid][c];
    nrm[(size_t)seq * T_ + rg * 64 + tid] = s;
  }
}

// ---------------------------------------------------------------------------
// Kernel 1 (FUSED): MFMA gemm from precomputed split-bf16 (blockIdx.y < npc)
// + mmd_l2 (blockIdx.y == npc). Fragments load DIRECTLY from global bf16
// (k-map = 8*(lane>>4)+e for BOTH A and B -> symmetric, HW k-perm cancels;
// same map the r18 XOR-involution produced). No LDS, no barriers, no
// conversion. Epilogue byte-identical to r18/r21 (verified absmax 0).
// ---------------------------------------------------------------------------
__global__ __launch_bounds__(256) void gemm_mmd_kernel(
    const float* __restrict__ data, float* __restrict__ wbuf, int pair0,
    int npc, float* __restrict__ l2buf, float* __restrict__ bwpart,
    const ushort_t* __restrict__ xh, const ushort_t* __restrict__ xl,
    const float* __restrict__ nrm) {
  if ((int)blockIdx.y == npc) {
    const int tid = threadIdx.x;
    const int g = tid >> 6;
    const int f = tid & 63;
    const int b = (int)blockIdx.x * 4 + g;
    if (b < 253) {
      int u = 0, rem = b;
      while (rem >= 22 - u) { rem -= 22 - u; ++u; }
      int v = u + rem;
      float s = 0.f;
      if (u != v) {
        int iu = u < 11 ? u : u + 5;
        int iv = v < 11 ? v : v + 5;
        const float* A = data + (size_t)iu * (T_ * DF) + f;
        const float* B = data + (size_t)iv * (T_ * DF) + f;
#pragma unroll 8
        for (int t = 0; t < T_; ++t) {
          float dd = A[(size_t)t * DF] - B[(size_t)t * DF];
          s = fmaf(dd, dd, s);
        }
      }
      l2buf[(size_t)(u * 22 + v) * 64 + f] = s;
      l2buf[(size_t)(v * 22 + u) * 64 + f] = s;
      float tot = wred_sum(s);
      if (f == 0) bwpart[b] = 2.f * tot;
    }
    return;
  }

  const int tile = blockIdx.x;   // 0..63 = (bi<<3)|bj
  const int pc = blockIdx.y;
  const int p = pair0 + pc;
  const int w = p / 15;
  const int o = p - w * 15;
  const int aidx = w * STEPW;
  const int oidx = aidx + 1 + o;
  const int i0 = (tile >> 3) << 6;
  const int j0 = (tile & 7) << 6;
  const int tid = threadIdx.x;
  const int lane = tid & 63;
  const int wid = tid >> 6;
  const int b16 = lane >> 4;      // k-block 0..3
  const int kof = 8 * b16;        // k offset of fragment half 0

  const ushort_t* XHg = xh + (size_t)aidx * (T_ * DF);
  const ushort_t* XLg = xl + (size_t)aidx * (T_ * DF);
  const ushort_t* YHg = xh + (size_t)oidx * (T_ * DF);
  const ushort_t* YLg = xl + (size_t)oidx * (T_ * DF);
  const float* nrmX = nrm + (size_t)aidx * T_;
  const float* nrmY = nrm + (size_t)oidx * T_;

  // A fragments: row i0 + 16*wid + (lane&15), k = kof..kof+7 and +32
  const int rowAg = i0 + 16 * wid + (lane & 15);
  const size_t abase = (size_t)rowAg * DF + kof;
  bf16x8 ah0 = *reinterpret_cast<const bf16x8*>(&XHg[abase]);
  bf16x8 ah1 = *reinterpret_cast<const bf16x8*>(&XHg[abase + 32]);
  bf16x8 al0 = *reinterpret_cast<const bf16x8*>(&XLg[abase]);
  bf16x8 al1 = *reinterpret_cast<const bf16x8*>(&XLg[abase + 32]);

  // my 4 output-row norms (contiguous float4, 16B-aligned)
  const float4 nxv =
      *reinterpret_cast<const float4*>(&nrmX[i0 + 16 * wid + 4 * b16]);
  const float nx[4] = {nxv.x, nxv.y, nxv.z, nxv.w};

  float* WpBase = wbuf + (size_t)pc * (NSK * T_);

#pragma unroll
  for (int t = 0; t < 4; ++t) {
    const int rowBg = j0 + 16 * t + (lane & 15);
    const size_t bbase = (size_t)rowBg * DF + kof;
    bf16x8 bh0 = *reinterpret_cast<const bf16x8*>(&YHg[bbase]);
    bf16x8 bh1 = *reinterpret_cast<const bf16x8*>(&YHg[bbase + 32]);
    bf16x8 bl0 = *reinterpret_cast<const bf16x8*>(&YLg[bbase]);
    bf16x8 bl1 = *reinterpret_cast<const bf16x8*>(&YLg[bbase + 32]);

    f32x4 acc = {0.f, 0.f, 0.f, 0.f};
    acc = __builtin_amdgcn_mfma_f32_16x16x32_bf16(ah0, bh0, acc, 0, 0, 0);
    acc = __builtin_amdgcn_mfma_f32_16x16x32_bf16(ah1, bh1, acc, 0, 0, 0);
    acc = __builtin_amdgcn_mfma_f32_16x16x32_bf16(ah0, bl0, acc, 0, 0, 0);
    acc = __builtin_amdgcn_mfma_f32_16x16x32_bf16(ah1, bl1, acc, 0, 0, 0);
    acc = __builtin_amdgcn_mfma_f32_16x16x32_bf16(al0, bh0, acc, 0, 0, 0);
    acc = __builtin_amdgcn_mfma_f32_16x16x32_bf16(al1, bh1, acc, 0, 0, 0);

    // epilogue (r18-verified): element (i,j); col=lane&15, row=4*b16+r
    const int jg = j0 + 16 * t + (lane & 15);
    const float ny = nrmY[rowBg];
    const int g8 = jg >> 3;
    const int off = (((jg >> 2) & 1) << 8) + 4 * g8 + (jg & 3);
#pragma unroll
    for (int r = 0; r < 4; ++r) {
      const int ig = i0 + 16 * wid + 4 * b16 + r;
      float d = nx[r] + ny - 2.f * acc[r];
      float wv = __builtin_exp2f(-d * C1_);
      WpBase[(size_t)(ig + 2 * g8) * T_ + off] = wv;
    }
  }
}

// ---------------------------------------------------------------------------
// Kernel 2 (FUSED): dtw (blockIdx.x < npc) + mmd_k (blockIdx.x >= npc).
// BYTE-IDENTICAL to r21 (passed, absmax 0): fp64 mantissas + block exponent,
// register-staged W (vmcnt(12)), hoisted sum-tree exponent pSE.
// ---------------------------------------------------------------------------
__global__ __launch_bounds__(64) void dtw_mmdk_kernel(
    const float* __restrict__ Wm, const int* __restrict__ lens,
    float* __restrict__ dist, int pair0, int npc,
    const float* __restrict__ l2buf, const float* __restrict__ bwpart,
    float* __restrict__ mmdpart) {
  if ((int)blockIdx.x >= npc) {
    int b = (int)blockIdx.x - npc;  // 0..120
    if (b < 121) {
      int a = b / 11, c = b - a * 11;
      int f = threadIdx.x;
      float bs = 0.f;
      for (int k2 = f; k2 < 253; k2 += 64) bs += bwpart[k2];
      bs = wred_sum(bs);
      float bw = __shfl(bs, 0) * (1.f / (462.f * 4.f));
      float xx = l2buf[(size_t)(a * 22 + c) * 64 + f];
      float yy = l2buf[(size_t)((11 + a) * 22 + (11 + c)) * 64 + f];
      float xy = l2buf[(size_t)(a * 22 + (11 + c)) * 64 + f];
      float yx = l2buf[(size_t)((11 + a) * 22 + c) * 64 + f];
      float term = 0.f;
      float ib = 1.f / bw;
#pragma unroll
      for (int i = 0; i < 5; ++i) {
        term += expf(-xx * ib) + expf(-yy * ib) - expf(-xy * ib)
              - expf(-yx * ib);
        ib *= 0.5f;
      }
      float tt = wred_sum(term);
      if (f == 0) mmdpart[b] = tt;
    }
    return;
  }

  const int pc = blockIdx.x;
  const int p = pair0 + pc;
  const int w = p / 15;
  const int o = p - w * 15;
  const int lx = lens[w * STEPW];
  const int ly = lens[w * STEPW + 1 + o];
  const int l = threadIdx.x;
  const int imax = lx - 1;
  const int jt = ly - 1;
  const int lt = jt >> 3, ct = jt & 7;
  const int M = lt + (imax >> 1);
  const float invl = 1.f / (float)(lx + ly);

  const float* wp = Wm + (size_t)pc * (NSK * T_) + 4 * l;

  float4 K0a, K0b, K1a, K1b, K2a, K2b, K3a, K3b;
  float4 K4a, K4b, K5a, K5b, K6a, K6b, K7a, K7b;
  float4 K8a, K8b, K9a, K9b, K10a, K10b, K11a, K11b;

#define LDROW(A, B, R)                                     \
  {                                                        \
    int r_ = (R); r_ = r_ > 637 ? 637 : r_;                \
    const float* p_ = wp + (size_t)r_ * T_;                \
    GLOAD(A, p_); GLOAD(B, p_ + 256);                      \
  }

  LDROW(K0a, K0b, 0); LDROW(K1a, K1b, 1);
  LDROW(K2a, K2b, 2); LDROW(K3a, K3b, 3);
  LDROW(K4a, K4b, 4); LDROW(K5a, K5b, 5);

  double e0 = 0., e1 = 0., e2 = 0., e3 = 0.;
  double e4 = 0., e5 = 0., e6 = 0., e7 = 0.;
  int S = NEGS;
  int pSE = -1023;
  double sendA_v = 0.;  int sendA_s = NEGS;
  double rAv = 0.;  int rAs = NEGS;
  double pvB = 0.;  int psB = NEGS;

#define SUP(MM, SA0, SA1, SB0, SB1, RA0, RA1, RB0, RB1)                    \
  {                                                                        \
    const int m_ = (MM);                                                   \
    double nvB = __shfl_up(e7, 1);                                         \
    LDROW(RA0, RA1, 2 * m_ + 6);                                           \
    LDROW(RB0, RB1, 2 * m_ + 7);                                           \
    asm volatile("s_waitcnt vmcnt(12)" ::: "memory");                      \
    __builtin_amdgcn_sched_barrier(0);                                     \
    const int i = 2 * (m_ - l);                                            \
    double lA = rAv, dA = pvB, lB = nvB, dB2 = rAv;                        \
    int slA = rAs, sdA = psB, slB = rAs, sdB = rAs;                        \
    if (l == 0) {                                                          \
      lA = 0.; slA = NEGS;                                                 \
      dA = (i == 0) ? 1. : 0.; sdA = (i == 0) ? 0 : NEGS;                  \
      lB = 0.; slB = NEGS;                                                 \
      dB2 = 0.; sdB = NEGS;                                                \
    }                                                                      \
    if ((unsigned)i <= (unsigned)imax) {                                   \
      int NA = max(S + pSE, max(slA + dexp(lA), sdA + dexp(dA)));          \
      const int dS = S - NA;                                               \
      if (dS != 0) {                                                       \
        e0 = ldexp(e0, dS); e1 = ldexp(e1, dS);                            \
        e2 = ldexp(e2, dS); e3 = ldexp(e3, dS);                            \
        e4 = ldexp(e4, dS); e5 = ldexp(e5, dS);                            \
        e6 = ldexp(e6, dS); e7 = ldexp(e7, dS);                            \
      }                                                                    \
      double L = ldexp(lA, slA - NA);                                      \
      double G = ldexp(dA, sdA - NA);                                      \
      const double WA0 = (double)SA0.x, WA1 = (double)SA0.y;               \
      const double WA2 = (double)SA0.z, WA3 = (double)SA0.w;               \
      const double WA4 = (double)SA1.x, WA5 = (double)SA1.y;               \
      const double WA6 = (double)SA1.z, WA7 = (double)SA1.w;               \
      double qa0 = WA0 * ((L + G) + e0);                                   \
      double qa1 = WA1 * (e1 + e0);                                        \
      double qa2 = WA2 * (e2 + e1);                                        \
      double qa3 = WA3 * (e3 + e2);                                        \
      double qa4 = WA4 * (e4 + e3);                                        \
      double qa5 = WA5 * (e5 + e4);                                        \
      double qa6 = WA6 * (e6 + e5);                                        \
      double qa7 = WA7 * (e7 + e6);                                        \
      double a0 = qa0;                                                     \
      double a1 = fma(WA1, a0, qa1);                                       \
      double a2 = fma(WA2, a1, qa2);                                       \
      double a3 = fma(WA3, a2, qa3);                                       \
      double a4 = fma(WA4, a3, qa4);                                       \
      double a5 = fma(WA5, a4, qa5);                                       \
      double a6 = fma(WA6, a5, qa6);                                       \
      double a7 = fma(WA7, a6, qa7);                                       \
      if (i + 1 <= imax) {                                                 \
        int NB = max(NA, max(slB + dexp(lB), sdB + dexp(dB2)));            \
        const int dB = NA - NB;                                            \
        if (dB != 0) {                                                     \
          a0 = ldexp(a0, dB); a1 = ldexp(a1, dB);                          \
          a2 = ldexp(a2, dB); a3 = ldexp(a3, dB);                          \
          a4 = ldexp(a4, dB); a5 = ldexp(a5, dB);                          \
          a6 = ldexp(a6, dB); a7 = ldexp(a7, dB);                          \
        }                                                                  \
        sendA_v = a7; sendA_s = NB;                                        \
        double LB = ldexp(lB, slB - NB);                                   \
        double GB = ldexp(dB2, sdB - NB);                                  \
        const double WB0 = (double)SB0.x, WB1 = (double)SB0.y;             \
        const double WB2 = (double)SB0.z, WB3 = (double)SB0.w;             \
        const double WB4 = (double)SB1.x, WB5 = (double)SB1.y;             \
        const double WB6 = (double)SB1.z, WB7 = (double)SB1.w;             \
        double qb0 = WB0 * ((LB + GB) + a0);                               \
        double qb1 = WB1 * (a1 + a0);                                      \
        double qb2 = WB2 * (a2 + a1);                                      \
        double qb3 = WB3 * (a3 + a2);                                      \
        double qb4 = WB4 * (a4 + a3);                                      \
        double qb5 = WB5 * (a5 + a4);                                      \
        double qb6 = WB6 * (a6 + a5);                                      \
        double qb7 = WB7 * (a7 + a6);                                      \
        e0 = qb0;                                                          \
        e1 = fma(WB1, e0, qb1);                                            \
        e2 = fma(WB2, e1, qb2);                                            \
        e3 = fma(WB3, e2, qb3);                                            \
        e4 = fma(WB4, e3, qb4);                                            \
        e5 = fma(WB5, e4, qb5);                                            \
        e6 = fma(WB6, e5, qb6);                                            \
        e7 = fma(WB7, e6, qb7);                                            \
        S = NB;                                                            \
      } else {                                                             \
        e0 = a0; e1 = a1; e2 = a2; e3 = a3;                                \
        e4 = a4; e5 = a5; e6 = a6; e7 = a7;                                \
        sendA_v = a7; sendA_s = NA;                                        \
        S = NA;                                                            \
      }                                                                    \
      double sumN = ((e0 + e1) + (e2 + e3)) + ((e4 + e5) + (e6 + e7));     \
      pSE = dexp(sumN);                                                    \
    }                                                                      \
    pvB = nvB; psB = rAs;                                                  \
    rAv = __shfl_up(sendA_v, 1);                                           \
    rAs = __shfl_up(sendA_s, 1);                                           \
  }

  const int nsup = (M + 6) / 6 * 6;
  for (int mb = 0; mb < nsup; mb += 6) {
    SUP(mb + 0, K0a, K0b, K1a, K1b, K6a, K6b, K7a, K7b);
    SUP(mb + 1, K2a, K2b, K3a, K3b, K8a, K8b, K9a, K9b);
    SUP(mb + 2, K4a, K4b, K5a, K5b, K10a, K10b, K11a, K11b);
    SUP(mb + 3, K6a, K6b, K7a, K7b, K0a, K0b, K1a, K1b);
    SUP(mb + 4, K8a, K8b, K9a, K9b, K2a, K2b, K3a, K3b);
    SUP(mb + 5, K10a, K10b, K11a, K11b, K4a, K4b, K5a, K5b);
  }

  asm volatile("s_waitcnt vmcnt(0)" ::: "memory");

  if (l == lt) {
    double out_v = (ct == 0) ? e0 : (ct == 1) ? e1 : (ct == 2) ? e2
                 : (ct == 3) ? e3 : (ct == 4) ? e4 : (ct == 5) ? e5
                 : (ct == 6) ? e6 : e7;
    double vv = (out_v > 0.) ? out_v : 1e-300;
    double r = -C2D * (log2(vv) + (double)S);
    dist[p] = (float)(r * (double)invl);
  }
}

// ---------------------------------------------------------------------------
// Kernel 3: finalize — triplet loss + variance + MMD mean -> out[0]
// ---------------------------------------------------------------------------
__global__ __launch_bounds__(64) void finalize_kernel(
    const float* __restrict__ dist, const float* __restrict__ mmdpart,
    float* __restrict__ out) {
  int lane = threadIdx.x;
  float lv_po = 0.f;
  float dg[5];
#pragma unroll
  for (int g = 0; g < 5; ++g) dg[g] = 0.f;
  if (lane < 8) {
    const float* dr = dist + lane * 15;
    float dn[10];
#pragma unroll
    for (int g = 0; g < 5; ++g) dg[g] = dr[g];
#pragma unroll
    for (int k = 0; k < 10; ++k) dn[k] = dr[5 + k];
    float s1 = 0.f, s2 = 0.f;
    int nz = 0;
#pragma unroll
    for (int g = 0; g < 5; ++g) {
#pragma unroll
      for (int k = 0; k < 5; ++k) {
        float v2 = dg[g] + 1.0f - dn[k];
        if (v2 > 0.f) { s1 += v2; ++nz; }
      }
#pragma unroll
      for (int k = 5; k < 10; ++k) {
        float v2 = dg[g] + 1.0f - dn[k];
        if (v2 > 0.f) { s2 += v2; ++nz; }
      }
    }
    float only_pos = (dg[0] + dg[1] + dg[2] + dg[3] + dg[4]) * 0.002f;
    float lv = (s1 * 0.7f + s2 * 0.3f) / (float)(nz + 1);
    lv_po = lv + only_pos;
  }
  float tl = wred_sum(lv_po);
  tl = __shfl(tl, 0);

  float psum = dg[0] + dg[1] + dg[2] + dg[3] + dg[4];
  float tsum = wred_sum(psum);
  float mean = __shfl(tsum, 0) * (1.f / 40.f);
  float pdev = 0.f;
  if (lane < 8) {
#pragma unroll
    for (int g = 0; g < 5; ++g) {
      float dd = dg[g] - mean;
      pdev = fmaf(dd, dd, pdev);
    }
  }
  float tdev = wred_sum(pdev);
  tdev = __shfl(tdev, 0);

  float msum = 0.f;
  for (int k2 = lane; k2 < 121; k2 += 64) msum += mmdpart[k2];
  float mt = wred_sum(msum);

  if (lane == 0) {
    float total_loss = tl * (1.f / 8.f);
    float var_g = (tdev / 39.f) * 0.1f;
    float mmd = mt * (1.f / 7744.f);
    out[0] = total_loss + mmd + var_g;
  }
}

__global__ __launch_bounds__(64) void zero_out_kernel(float* __restrict__ out,
                                                      int n) {
  int i = blockIdx.x * 64 + threadIdx.x;
  if (i < n) out[i] = 0.f;
}

// ---------------------------------------------------------------------------
extern "C" void kernel_launch(void* const* d_in, const int* in_sizes, int n_in,
                              void* d_out, int out_size, void* d_ws,
                              size_t ws_size, hipStream_t stream) {
  const float* data = (const float*)d_in[0];
  const int* lens = (const int*)d_in[1];
  float* out = (float*)d_out;
  char* ws = (char*)d_ws;

  const size_t HDR = 131072;                       // dist/bwpart/mmdpart/l2buf
  const size_t NRM_OFF = HDR;                      // 128*512*4 = 256 KB
  const size_t XH_OFF = NRM_OFF + 262144;          // 8 MB
  const size_t XL_OFF = XH_OFF + 8388608;          // 8 MB
  const size_t WB_OFF = XL_OFF + 8388608;          // = 17,170,432 B
  const size_t per_pair = (size_t)NSK * T_ * sizeof(float);  // 1.31 MB

  if (ws_size < WB_OFF + per_pair) {
    zero_out_kernel<<<dim3((out_size + 63) / 64), 64, 0, stream>>>(out,
                                                                   out_size);
    return;
  }

  float* dist = (float*)(ws + 0);
  float* bwpart = (float*)(ws + 1024);
  float* mmdpart = (float*)(ws + 3072);
  float* l2buf = (float*)(ws + 4096);
  float* nrm = (float*)(ws + NRM_OFF);
  ushort_t* xh = (ushort_t*)(ws + XH_OFF);
  ushort_t* xl = (ushort_t*)(ws + XL_OFF);
  float* wbuf = (float*)(ws + WB_OFF);

  size_t avail = ws_size - WB_OFF;
  int PC = (int)(avail / per_pair);
  if (PC > NPAIR) PC = NPAIR;

  prep_kernel<<<dim3(NSEQ * 8), 256, 0, stream>>>(data, xh, xl, nrm);

  for (int p0 = 0; p0 < NPAIR; p0 += PC) {
    int pc = (NPAIR - p0) < PC ? (NPAIR - p0) : PC;
    int first = (p0 == 0) ? 1 : 0;
    gemm_mmd_kernel<<<dim3(64, pc + first), 256, 0, stream>>>(
        data, wbuf, p0, pc, l2buf, bwpart, xh, xl, nrm);
    dtw_mmdk_kernel<<<dim3(pc + (first ? 121 : 0)), 64, 0, stream>>>(
        wbuf, lens, dist, p0, pc, l2buf, bwpart, mmdpart);
  }
  finalize_kernel<<<dim3(1), 64, 0, stream>>>(dist, mmdpart, out);
}

// Round 23
// 180.196 us; speedup vs baseline: 1.2834x; 1.2834x over previous
//
#include <hip/hip_runtime.h>
#include <hip/hip_bf16.h>
#include <cstdint>
#include <cstddef>

#define T_ 512
#define DF 64
#define NPAIR 120
#define STEPW 16
#define NEGS (-(1 << 26))
#define NSK 640   // skewed-W rows per pair (638 used, padded)

// softmin constants
#define C1_ 0.28853900817779268f   // log2(e)/5
#define C2D 3.4657359027997265     // 5*ln(2), double

typedef unsigned short ushort_t;
using f32x4 = __attribute__((ext_vector_type(4))) float;
using bf16x8 = __attribute__((ext_vector_type(8))) short;

__device__ __forceinline__ float wred_sum(float v) {
#pragma unroll
  for (int o = 32; o > 0; o >>= 1) v += __shfl_down(v, o);
  return v;  // lane 0 holds the total
}

__device__ __forceinline__ int dexp(double x) {
  return (int)((__double_as_longlong(x) >> 52) & 0x7ff) - 1023;
}

__device__ __forceinline__ ushort_t f2bf(float x) {
  __hip_bfloat16 h = __float2bfloat16(x);
  return *reinterpret_cast<ushort_t*>(&h);
}
__device__ __forceinline__ float bf2f(ushort_t u) {
  __hip_bfloat16 h = *reinterpret_cast<__hip_bfloat16*>(&u);
  return __bfloat162float(h);
}

// unsinkable 16B global load to a named VGPR quad (HK pattern)
#define GLOAD(DST, PTR)                                                    \
  asm volatile("global_load_dwordx4 %0, %1, off"                           \
               : "=&v"(DST) : "v"(PTR) : "memory")

// ---------------------------------------------------------------------------
// Kernel 1 (FUSED): MFMA bf16-split gemm (blockIdx.y < npc) + mmd_l2
// (blockIdx.y == npc).  Byte-identical to r18/r19 (verified absmax 0,
// best total 180.1 us). r22's prep+direct-global variant REGRESSED (231us):
// scattered 16B fragment gathers from global lost to LDS reuse.
// ---------------------------------------------------------------------------
__global__ __launch_bounds__(256) void gemm_mmd_kernel(
    const float* __restrict__ data, float* __restrict__ wbuf, int pair0,
    int npc, float* __restrict__ l2buf, float* __restrict__ bwpart) {
  __shared__ ushort_t XH[4096], XL[4096], YH[4096], YL[4096];  // 64x64 bf16
  __shared__ float nrmx[64];
  __shared__ float nrmy[64];

  if ((int)blockIdx.y == npc) {
    const int tid = threadIdx.x;
    const int g = tid >> 6;
    const int f = tid & 63;
    const int b = (int)blockIdx.x * 4 + g;
    if (b < 253) {
      int u = 0, rem = b;
      while (rem >= 22 - u) { rem -= 22 - u; ++u; }
      int v = u + rem;
      float s = 0.f;
      if (u != v) {
        int iu = u < 11 ? u : u + 5;
        int iv = v < 11 ? v : v + 5;
        const float* A = data + (size_t)iu * (T_ * DF) + f;
        const float* B = data + (size_t)iv * (T_ * DF) + f;
#pragma unroll 8
        for (int t = 0; t < T_; ++t) {
          float dd = A[(size_t)t * DF] - B[(size_t)t * DF];
          s = fmaf(dd, dd, s);
        }
      }
      l2buf[(size_t)(u * 22 + v) * 64 + f] = s;
      l2buf[(size_t)(v * 22 + u) * 64 + f] = s;
      float tot = wred_sum(s);
      if (f == 0) bwpart[b] = 2.f * tot;
    }
    return;
  }

  const int tile = blockIdx.x;   // 0..63 = (bi<<3)|bj
  const int pc = blockIdx.y;
  const int p = pair0 + pc;
  const int w = p / 15;
  const int o = p - w * 15;
  const int aidx = w * STEPW;
  const int oidx = aidx + 1 + o;
  const int i0 = (tile >> 3) << 6;
  const int j0 = (tile & 7) << 6;
  const int tid = threadIdx.x;

  const float* Xg = data + (size_t)aidx * (T_ * DF);
  const float* Yg = data + (size_t)oidx * (T_ * DF);

#pragma unroll
  for (int l = 0; l < 4; ++l) {
    int idx = tid + l * 256;  // 0..1023
    int r = idx >> 4;
    int c = idx & 15;
    int g = c >> 1, h = c & 1;
    int base = r * 64 + ((g ^ (r & 7)) << 3) + (h << 2);
    float4 xv = reinterpret_cast<const float4*>(Xg + (size_t)(i0 + r) * DF)[c];
    float4 yv = reinterpret_cast<const float4*>(Yg + (size_t)(j0 + r) * DF)[c];
    const float xa[4] = {xv.x, xv.y, xv.z, xv.w};
    const float ya[4] = {yv.x, yv.y, yv.z, yv.w};
#pragma unroll
    for (int e = 0; e < 4; ++e) {
      ushort_t xh = f2bf(xa[e]);
      XH[base + e] = xh;
      XL[base + e] = f2bf(xa[e] - bf2f(xh));
      ushort_t yh = f2bf(ya[e]);
      YH[base + e] = yh;
      YL[base + e] = f2bf(ya[e] - bf2f(yh));
    }
  }
  __syncthreads();

  if (tid < 128) {
    int r = tid & 63;
    float s = 0.f;
    if (tid < 64) {
#pragma unroll
      for (int k = 0; k < 64; ++k) {
        int a = r * 64 + (((k >> 3) ^ (r & 7)) << 3) + (k & 7);
        float x = bf2f(XH[a]) + bf2f(XL[a]);
        s = fmaf(x, x, s);
      }
      nrmx[r] = s;
    } else {
#pragma unroll
      for (int k = 0; k < 64; ++k) {
        int a = r * 64 + (((k >> 3) ^ (r & 7)) << 3) + (k & 7);
        float y = bf2f(YH[a]) + bf2f(YL[a]);
        s = fmaf(y, y, s);
      }
      nrmy[r] = s;
    }
  }
  __syncthreads();

  const int lane = tid & 63;
  const int wid = tid >> 6;
  const int rowA = 16 * wid + (lane & 15);
  const int b16 = lane >> 4;

  const int aA0 = rowA * 64 + (((b16) ^ (rowA & 7)) << 3);
  const int aA1 = rowA * 64 + (((4 + b16) ^ (rowA & 7)) << 3);
  bf16x8 ah0 = *reinterpret_cast<const bf16x8*>(&XH[aA0]);
  bf16x8 ah1 = *reinterpret_cast<const bf16x8*>(&XH[aA1]);
  bf16x8 al0 = *reinterpret_cast<const bf16x8*>(&XL[aA0]);
  bf16x8 al1 = *reinterpret_cast<const bf16x8*>(&XL[aA1]);

  float* WpBase = wbuf + (size_t)pc * (NSK * T_);

#pragma unroll
  for (int t = 0; t < 4; ++t) {
    const int rowB = 16 * t + (lane & 15);
    const int aB0 = rowB * 64 + (((b16) ^ (rowB & 7)) << 3);
    const int aB1 = rowB * 64 + (((4 + b16) ^ (rowB & 7)) << 3);
    bf16x8 bh0 = *reinterpret_cast<const bf16x8*>(&YH[aB0]);
    bf16x8 bh1 = *reinterpret_cast<const bf16x8*>(&YH[aB1]);
    bf16x8 bl0 = *reinterpret_cast<const bf16x8*>(&YL[aB0]);
    bf16x8 bl1 = *reinterpret_cast<const bf16x8*>(&YL[aB1]);

    f32x4 acc = {0.f, 0.f, 0.f, 0.f};
    acc = __builtin_amdgcn_mfma_f32_16x16x32_bf16(ah0, bh0, acc, 0, 0, 0);
    acc = __builtin_amdgcn_mfma_f32_16x16x32_bf16(ah1, bh1, acc, 0, 0, 0);
    acc = __builtin_amdgcn_mfma_f32_16x16x32_bf16(ah0, bl0, acc, 0, 0, 0);
    acc = __builtin_amdgcn_mfma_f32_16x16x32_bf16(ah1, bl1, acc, 0, 0, 0);
    acc = __builtin_amdgcn_mfma_f32_16x16x32_bf16(al0, bh0, acc, 0, 0, 0);
    acc = __builtin_amdgcn_mfma_f32_16x16x32_bf16(al1, bh1, acc, 0, 0, 0);

    const int jg = j0 + 16 * t + (lane & 15);
    const float ny = nrmy[16 * t + (lane & 15)];
    const int g8 = jg >> 3;
    const int off = (((jg >> 2) & 1) << 8) + 4 * g8 + (jg & 3);
#pragma unroll
    for (int r = 0; r < 4; ++r) {
      const int ig = i0 + 16 * wid + 4 * b16 + r;
      float d = nrmx[16 * wid + 4 * b16 + r] + ny - 2.f * acc[r];
      float wv = __builtin_exp2f(-d * C1_);
      WpBase[(size_t)(ig + 2 * g8) * T_ + off] = wv;
    }
  }
}

// ---------------------------------------------------------------------------
// Kernel 2 (FUSED): dtw (blockIdx.x < npc) + mmd_k (blockIdx.x >= npc).
// Byte-identical to r19 (verified absmax 0): fp64 mantissas + block
// exponent, register-staged W (vmcnt(12)), off-path boundary shuffles.
// ---------------------------------------------------------------------------
__global__ __launch_bounds__(64) void dtw_mmdk_kernel(
    const float* __restrict__ Wm, const int* __restrict__ lens,
    float* __restrict__ dist, int pair0, int npc,
    const float* __restrict__ l2buf, const float* __restrict__ bwpart,
    float* __restrict__ mmdpart) {
  if ((int)blockIdx.x >= npc) {
    int b = (int)blockIdx.x - npc;  // 0..120
    if (b < 121) {
      int a = b / 11, c = b - a * 11;
      int f = threadIdx.x;
      float bs = 0.f;
      for (int k2 = f; k2 < 253; k2 += 64) bs += bwpart[k2];
      bs = wred_sum(bs);
      float bw = __shfl(bs, 0) * (1.f / (462.f * 4.f));
      float xx = l2buf[(size_t)(a * 22 + c) * 64 + f];
      float yy = l2buf[(size_t)((11 + a) * 22 + (11 + c)) * 64 + f];
      float xy = l2buf[(size_t)(a * 22 + (11 + c)) * 64 + f];
      float yx = l2buf[(size_t)((11 + a) * 22 + c) * 64 + f];
      float term = 0.f;
      float ib = 1.f / bw;
#pragma unroll
      for (int i = 0; i < 5; ++i) {
        term += expf(-xx * ib) + expf(-yy * ib) - expf(-xy * ib)
              - expf(-yx * ib);
        ib *= 0.5f;
      }
      float tt = wred_sum(term);
      if (f == 0) mmdpart[b] = tt;
    }
    return;
  }

  const int pc = blockIdx.x;
  const int p = pair0 + pc;
  const int w = p / 15;
  const int o = p - w * 15;
  const int lx = lens[w * STEPW];
  const int ly = lens[w * STEPW + 1 + o];
  const int l = threadIdx.x;
  const int imax = lx - 1;
  const int jt = ly - 1;
  const int lt = jt >> 3, ct = jt & 7;
  const int M = lt + (imax >> 1);
  const float invl = 1.f / (float)(lx + ly);

  const float* wp = Wm + (size_t)pc * (NSK * T_) + 4 * l;

  float4 K0a, K0b, K1a, K1b, K2a, K2b, K3a, K3b;
  float4 K4a, K4b, K5a, K5b, K6a, K6b, K7a, K7b;
  float4 K8a, K8b, K9a, K9b, K10a, K10b, K11a, K11b;

#define LDROW(A, B, R)                                     \
  {                                                        \
    int r_ = (R); r_ = r_ > 637 ? 637 : r_;                \
    const float* p_ = wp + (size_t)r_ * T_;                \
    GLOAD(A, p_); GLOAD(B, p_ + 256);                      \
  }

  LDROW(K0a, K0b, 0); LDROW(K1a, K1b, 1);
  LDROW(K2a, K2b, 2); LDROW(K3a, K3b, 3);
  LDROW(K4a, K4b, 4); LDROW(K5a, K5b, 5);

  // committed row-B E (fp64 mantissas, shared block exponent S)
  double e0 = 0., e1 = 0., e2 = 0., e3 = 0.;
  double e4 = 0., e5 = 0., e6 = 0., e7 = 0.;
  int S = NEGS;
  double sendA_v = 0.;  int sendA_s = NEGS;
  double rAv = 0.;  int rAs = NEGS;
  double pvB = 0.;  int psB = NEGS;

#define SUP(MM, SA0, SA1, SB0, SB1, RA0, RA1, RB0, RB1)                    \
  {                                                                        \
    const int m_ = (MM);                                                   \
    double nvB = __shfl_up(e7, 1);  /* row-B left; scale == rAs */         \
    LDROW(RA0, RA1, 2 * m_ + 6);                                           \
    LDROW(RB0, RB1, 2 * m_ + 7);                                           \
    asm volatile("s_waitcnt vmcnt(12)" ::: "memory");                      \
    __builtin_amdgcn_sched_barrier(0);                                     \
    const int i = 2 * (m_ - l);                                            \
    double lA = rAv, dA = pvB, lB = nvB, dB2 = rAv;                        \
    int slA = rAs, sdA = psB, slB = rAs, sdB = rAs;                        \
    if (l == 0) {                                                          \
      lA = 0.; slA = NEGS;                                                 \
      dA = (i == 0) ? 1. : 0.; sdA = (i == 0) ? 0 : NEGS;                  \
      lB = 0.; slB = NEGS;                                                 \
      dB2 = 0.; sdB = NEGS;                                                \
    }                                                                      \
    if ((unsigned)i <= (unsigned)imax) {                                   \
      double sum = ((e0 + e1) + (e2 + e3)) + ((e4 + e5) + (e6 + e7));      \
      int NA = max(S + dexp(sum), max(slA + dexp(lA), sdA + dexp(dA)));    \
      const int dS = S - NA;                                               \
      if (dS != 0) {                                                       \
        e0 = ldexp(e0, dS); e1 = ldexp(e1, dS);                            \
        e2 = ldexp(e2, dS); e3 = ldexp(e3, dS);                            \
        e4 = ldexp(e4, dS); e5 = ldexp(e5, dS);                            \
        e6 = ldexp(e6, dS); e7 = ldexp(e7, dS);                            \
      }                                                                    \
      double L = ldexp(lA, slA - NA);                                      \
      double G = ldexp(dA, sdA - NA);                                      \
      const double WA0 = (double)SA0.x, WA1 = (double)SA0.y;               \
      const double WA2 = (double)SA0.z, WA3 = (double)SA0.w;               \
      const double WA4 = (double)SA1.x, WA5 = (double)SA1.y;               \
      const double WA6 = (double)SA1.z, WA7 = (double)SA1.w;               \
      double qa0 = WA0 * ((L + G) + e0);                                   \
      double qa1 = WA1 * (e1 + e0);                                        \
      double qa2 = WA2 * (e2 + e1);                                        \
      double qa3 = WA3 * (e3 + e2);                                        \
      double qa4 = WA4 * (e4 + e3);                                        \
      double qa5 = WA5 * (e5 + e4);                                        \
      double qa6 = WA6 * (e6 + e5);                                        \
      double qa7 = WA7 * (e7 + e6);                                        \
      double a0 = qa0;                                                     \
      double a1 = fma(WA1, a0, qa1);                                       \
      double a2 = fma(WA2, a1, qa2);                                       \
      double a3 = fma(WA3, a2, qa3);                                       \
      double a4 = fma(WA4, a3, qa4);                                       \
      double a5 = fma(WA5, a4, qa5);                                       \
      double a6 = fma(WA6, a5, qa6);                                       \
      double a7 = fma(WA7, a6, qa7);                                       \
      if (i + 1 <= imax) {                                                 \
        int NB = max(NA, max(slB + dexp(lB), sdB + dexp(dB2)));            \
        const int dB = NA - NB;                                            \
        if (dB != 0) {                                                     \
          a0 = ldexp(a0, dB); a1 = ldexp(a1, dB);                          \
          a2 = ldexp(a2, dB); a3 = ldexp(a3, dB);                          \
          a4 = ldexp(a4, dB); a5 = ldexp(a5, dB);                          \
          a6 = ldexp(a6, dB); a7 = ldexp(a7, dB);                          \
        }                                                                  \
        sendA_v = a7; sendA_s = NB;                                        \
        double LB = ldexp(lB, slB - NB);                                   \
        double GB = ldexp(dB2, sdB - NB);                                  \
        const double WB0 = (double)SB0.x, WB1 = (double)SB0.y;             \
        const double WB2 = (double)SB0.z, WB3 = (double)SB0.w;             \
        const double WB4 = (double)SB1.x, WB5 = (double)SB1.y;             \
        const double WB6 = (double)SB1.z, WB7 = (double)SB1.w;             \
        double qb0 = WB0 * ((LB + GB) + a0);                               \
        double qb1 = WB1 * (a1 + a0);                                      \
        double qb2 = WB2 * (a2 + a1);                                      \
        double qb3 = WB3 * (a3 + a2);                                      \
        double qb4 = WB4 * (a4 + a3);                                      \
        double qb5 = WB5 * (a5 + a4);                                      \
        double qb6 = WB6 * (a6 + a5);                                      \
        double qb7 = WB7 * (a7 + a6);                                      \
        e0 = qb0;                                                          \
        e1 = fma(WB1, e0, qb1);                                            \
        e2 = fma(WB2, e1, qb2);                                            \
        e3 = fma(WB3, e2, qb3);                                            \
        e4 = fma(WB4, e3, qb4);                                            \
        e5 = fma(WB5, e4, qb5);                                            \
        e6 = fma(WB6, e5, qb6);                                            \
        e7 = fma(WB7, e6, qb7);                                            \
        S = NB;                                                            \
      } else {                                                             \
        e0 = a0; e1 = a1; e2 = a2; e3 = a3;                                \
        e4 = a4; e5 = a5; e6 = a6; e7 = a7;                                \
        sendA_v = a7; sendA_s = NA;                                        \
        S = NA;                                                            \
      }                                                                    \
    }                                                                      \
    pvB = nvB; psB = rAs;                                                  \
    rAv = __shfl_up(sendA_v, 1);                                           \
    rAs = __shfl_up(sendA_s, 1);                                           \
  }

  const int nsup = (M + 6) / 6 * 6;
  for (int mb = 0; mb < nsup; mb += 6) {
    SUP(mb + 0, K0a, K0b, K1a, K1b, K6a, K6b, K7a, K7b);
    SUP(mb + 1, K2a, K2b, K3a, K3b, K8a, K8b, K9a, K9b);
    SUP(mb + 2, K4a, K4b, K5a, K5b, K10a, K10b, K11a, K11b);
    SUP(mb + 3, K6a, K6b, K7a, K7b, K0a, K0b, K1a, K1b);
    SUP(mb + 4, K8a, K8b, K9a, K9b, K2a, K2b, K3a, K3b);
    SUP(mb + 5, K10a, K10b, K11a, K11b, K4a, K4b, K5a, K5b);
  }

  asm volatile("s_waitcnt vmcnt(0)" ::: "memory");

  if (l == lt) {
    double out_v = (ct == 0) ? e0 : (ct == 1) ? e1 : (ct == 2) ? e2
                 : (ct == 3) ? e3 : (ct == 4) ? e4 : (ct == 5) ? e5
                 : (ct == 6) ? e6 : e7;
    double vv = (out_v > 0.) ? out_v : 1e-300;
    double r = -C2D * (log2(vv) + (double)S);
    dist[p] = (float)(r * (double)invl);
  }
}

// ---------------------------------------------------------------------------
// Kernel 3: finalize — triplet loss + variance + MMD mean -> out[0]
// ---------------------------------------------------------------------------
__global__ __launch_bounds__(64) void finalize_kernel(
    const float* __restrict__ dist, const float* __restrict__ mmdpart,
    float* __restrict__ out) {
  int lane = threadIdx.x;
  float lv_po = 0.f;
  float dg[5];
#pragma unroll
  for (int g = 0; g < 5; ++g) dg[g] = 0.f;
  if (lane < 8) {
    const float* dr = dist + lane * 15;
    float dn[10];
#pragma unroll
    for (int g = 0; g < 5; ++g) dg[g] = dr[g];
#pragma unroll
    for (int k = 0; k < 10; ++k) dn[k] = dr[5 + k];
    float s1 = 0.f, s2 = 0.f;
    int nz = 0;
#pragma unroll
    for (int g = 0; g < 5; ++g) {
#pragma unroll
      for (int k = 0; k < 5; ++k) {
        float v2 = dg[g] + 1.0f - dn[k];
        if (v2 > 0.f) { s1 += v2; ++nz; }
      }
#pragma unroll
      for (int k = 5; k < 10; ++k) {
        float v2 = dg[g] + 1.0f - dn[k];
        if (v2 > 0.f) { s2 += v2; ++nz; }
      }
    }
    float only_pos = (dg[0] + dg[1] + dg[2] + dg[3] + dg[4]) * 0.002f;
    float lv = (s1 * 0.7f + s2 * 0.3f) / (float)(nz + 1);
    lv_po = lv + only_pos;
  }
  float tl = wred_sum(lv_po);
  tl = __shfl(tl, 0);

  float psum = dg[0] + dg[1] + dg[2] + dg[3] + dg[4];
  float tsum = wred_sum(psum);
  float mean = __shfl(tsum, 0) * (1.f / 40.f);
  float pdev = 0.f;
  if (lane < 8) {
#pragma unroll
    for (int g = 0; g < 5; ++g) {
      float dd = dg[g] - mean;
      pdev = fmaf(dd, dd, pdev);
    }
  }
  float tdev = wred_sum(pdev);
  tdev = __shfl(tdev, 0);

  float msum = 0.f;
  for (int k2 = lane; k2 < 121; k2 += 64) msum += mmdpart[k2];
  float mt = wred_sum(msum);

  if (lane == 0) {
    float total_loss = tl * (1.f / 8.f);
    float var_g = (tdev / 39.f) * 0.1f;
    float mmd = mt * (1.f / 7744.f);
    out[0] = total_loss + mmd + var_g;
  }
}

__global__ __launch_bounds__(64) void zero_out_kernel(float* __restrict__ out,
                                                      int n) {
  int i = blockIdx.x * 64 + threadIdx.x;
  if (i < n) out[i] = 0.f;
}

// ---------------------------------------------------------------------------
extern "C" void kernel_launch(void* const* d_in, const int* in_sizes, int n_in,
                              void* d_out, int out_size, void* d_ws,
                              size_t ws_size, hipStream_t stream) {
  const float* data = (const float*)d_in[0];
  const int* lens = (const int*)d_in[1];
  float* out = (float*)d_out;
  char* ws = (char*)d_ws;

  const size_t HDR = 131072;
  const size_t per_pair = (size_t)NSK * T_ * sizeof(float);  // 1.31 MB

  if (ws_size < HDR + per_pair) {
    zero_out_kernel<<<dim3((out_size + 63) / 64), 64, 0, stream>>>(out,
                                                                   out_size);
    return;
  }

  float* dist = (float*)(ws + 0);
  float* bwpart = (float*)(ws + 1024);
  float* mmdpart = (float*)(ws + 3072);
  float* l2buf = (float*)(ws + 4096);
  float* wbuf = (float*)(ws + HDR);

  size_t avail = ws_size - HDR;
  int PC = (int)(avail / per_pair);
  if (PC > NPAIR) PC = NPAIR;

  for (int p0 = 0; p0 < NPAIR; p0 += PC) {
    int pc = (NPAIR - p0) < PC ? (NPAIR - p0) : PC;
    int first = (p0 == 0) ? 1 : 0;
    gemm_mmd_kernel<<<dim3(64, pc + first), 256, 0, stream>>>(
        data, wbuf, p0, pc, l2buf, bwpart);
    dtw_mmdk_kernel<<<dim3(pc + (first ? 121 : 0)), 64, 0, stream>>>(
        wbuf, lens, dist, p0, pc, l2buf, bwpart, mmdpart);
  }
  finalize_kernel<<<dim3(1), 64, 0, stream>>>(dist, mmdpart, out);
}